// Round 9
// baseline (480.147 us; speedup 1.0000x reference)
//
#include <hip/hip_runtime.h>
#include <cstdint>
#include <cstddef>

#define NN 8192
#define FIN 256
#define FOUT 128
#define SLOPE 0.2f
#define SHIFT 8.0f

typedef float f32x4 __attribute__((ext_vector_type(4)));
typedef __bf16 bf16x8 __attribute__((ext_vector_type(8)));
typedef int i32x4 __attribute__((ext_vector_type(4)));
typedef unsigned int u32x4 __attribute__((ext_vector_type(4)));
typedef unsigned int u32x2 __attribute__((ext_vector_type(2)));

__device__ __forceinline__ unsigned short f2bf(float f) {
  return __builtin_bit_cast(unsigned short, (__bf16)f);
}
__device__ __forceinline__ float bf2f(unsigned short u) {
  return (float)__builtin_bit_cast(__bf16, u);
}

// async global->LDS DMA, 16 B/lane; LDS dest = wave-uniform base + lane*16
__device__ __forceinline__ void async_cp16(void* lds, const void* g) {
  __builtin_amdgcn_global_load_lds(
      (const __attribute__((address_space(1))) void*)g,
      (__attribute__((address_space(3))) void*)lds, 16, 0, 0);
}

// ---------------------------------------------------------------------------
// Kernel A: h = x @ W (fp32 acc) -> ht[FOUT][NN] bf16 (transposed), plus fused
// s-reductions and the exp-factor tables:
//   Etab[2row,2row+1] = (E, E2) = (e^{s1-c}, e^{0.2 s1 - c}),
//     c = leakyrelu(s1 + SHIFT)  (>= row max of leakyrelu(s1+s2))
//   FbfF[j] = bf16(e^{s2_j}),  FbfF2[j] = bf16(e^{0.2 s2_j})   (two planes)
// so exp(leakyrelu(s1+s2) - c) = max(E*F, E2*F2)  (exp monotone, exact).
// ---------------------------------------------------------------------------
__global__ __launch_bounds__(256, 4) void k_hw(const float* __restrict__ x,
                                               const float* __restrict__ W,
                                               const float* __restrict__ a1,
                                               const float* __restrict__ a2,
                                               unsigned short* __restrict__ ht,
                                               float* __restrict__ Etab,
                                               unsigned short* __restrict__ FbfF,
                                               unsigned short* __restrict__ FbfF2) {
  __shared__ float xs[8][256];
  __shared__ unsigned short tile[128][8];   // [f][row]
  const int tid = threadIdx.x;
  const int rowbase = blockIdx.x * 8;

  #pragma unroll
  for (int it = 0; it < 2; ++it) {
    int fi = it * 1024 + tid * 4;
    int r = fi >> 8, k = fi & 255;
    *(f32x4*)&xs[r][k] = *(const f32x4*)(x + (size_t)(rowbase + r) * FIN + k);
  }
  __syncthreads();

  const int r = tid >> 5;    // 0..7
  const int cg = tid & 31;   // cols cg*4..cg*4+3
  f32x4 acc = {0.f, 0.f, 0.f, 0.f};

  #pragma unroll 8
  for (int k = 0; k < FIN; ++k) {
    f32x4 wv = *(const f32x4*)(W + k * FOUT + cg * 4);
    float xv = xs[r][k];
    acc[0] += xv * wv[0];
    acc[1] += xv * wv[1];
    acc[2] += xv * wv[2];
    acc[3] += xv * wv[3];
  }

  #pragma unroll
  for (int c = 0; c < 4; ++c) tile[cg * 4 + c][r] = f2bf(acc[c]);

  // fused s-vectors
  f32x4 av1 = *(const f32x4*)(a1 + cg * 4);
  f32x4 av2 = *(const f32x4*)(a2 + cg * 4);
  float s1 = acc[0] * av1[0] + acc[1] * av1[1] + acc[2] * av1[2] + acc[3] * av1[3];
  float s2 = acc[0] * av2[0] + acc[1] * av2[1] + acc[2] * av2[2] + acc[3] * av2[3];
  #pragma unroll
  for (int off = 16; off > 0; off >>= 1) {
    s1 += __shfl_xor(s1, off, 64);
    s2 += __shfl_xor(s2, off, 64);
  }
  if (cg == 0) {
    const int row = rowbase + r;
    float c0 = s1 + SHIFT;
    float c = fmaxf(c0, SLOPE * c0);
    Etab[(size_t)row * 2]     = __expf(s1 - c);
    Etab[(size_t)row * 2 + 1] = __expf(SLOPE * s1 - c);
    FbfF[row]  = f2bf(__expf(s2));
    FbfF2[row] = f2bf(__expf(SLOPE * s2));
  }
  __syncthreads();

  if (tid < 128) {
    u32x4 v = *(const u32x4*)&tile[tid][0];
    *(u32x4*)(ht + (size_t)tid * NN + rowbase) = v;
  }
}

// ---------------------------------------------------------------------------
// Kernel B: fused masked-softmax aggregation, v9.
// Delta vs v8 (passed, 181 us, VALUBusy 42%):
//  * af (weight A-fragments) built ONCE per block into LDS by all 256 threads
//    (was: rebuilt identically by all 4 waves -> 4x redundant VALU).
//  * mid-chunk barrier is RAW s_barrier + s_waitcnt lgkmcnt(0) ONLY (0xC07F):
//    the chunk-(c+1) DMA stays in flight across it (a full __syncthreads
//    would drain vmcnt(0) and serialize on HBM latency).
//  * chunk loop: __syncthreads (drains DMA(c), issued a full chunk ago) ->
//    stage(c+1) -> build af(c) -> lgkm-barrier -> MFMA(c).
//  * staging swizzles / probe MFMAs / ones-MFMA denominator unchanged
//    (R7/R8-proven: 0 bank conflicts, absmax 0.00195).
// ---------------------------------------------------------------------------
__global__ __launch_bounds__(256, 2) void k_gat(const int* __restrict__ adj,
                                                const unsigned short* __restrict__ ht,
                                                const float* __restrict__ Etab,
                                                const unsigned short* __restrict__ FbfF,
                                                const unsigned short* __restrict__ FbfF2,
                                                const float* __restrict__ bias,
                                                float* __restrict__ out) {
  __shared__ int sA[2][16 * 64];             // 8 KB : adj, slot s of row r holds group s^r
  __shared__ unsigned short sH[2][128 * 64]; // 32 KB: ht, slot s of row f holds group s^(f&7)
  __shared__ unsigned short sF[2][128];      // 0.5 KB: [0,64)=F plane, [64,128)=F2 plane
  __shared__ unsigned short sAF[2][1024];    // 4 KB : A-frags, [k32][lane][8]

  const int tid = threadIdx.x;
  const int wave = tid >> 6;
  const int lane = tid & 63;
  const int quad = lane >> 4;
  const int m = lane & 15;                   // A-row / B-col label
  const int rowbase = blockIdx.x * 16;

  // ---- runtime layout probes (exact in bf16/fp32) ----
  bf16x8 pm, pinv, pones;
  #pragma unroll
  for (int jj = 0; jj < 8; ++jj) {
    pm[jj] = (__bf16)(float)m;
    pinv[jj] = (__bf16)0.03125f;
    pones[jj] = (__bf16)1.0f;
  }
  f32x4 z = {0.f, 0.f, 0.f, 0.f};
  f32x4 rp = __builtin_amdgcn_mfma_f32_16x16x32_bf16(pm, pinv, z, 0, 0, 0);
  f32x4 cp = __builtin_amdgcn_mfma_f32_16x16x32_bf16(pinv, pm, z, 0, 0, 0);
  int rowmap[4], colmap[4];
  #pragma unroll
  for (int r = 0; r < 4; ++r) {
    rowmap[r] = ((int)(rp[r] + 0.5f)) & 15;
    colmap[r] = ((int)(cp[r] + 0.5f)) & 15;
  }

  // ---- build-phase role: thread t builds 4 weight elements ----
  const int b_half = tid & 1;                // low/high half of an 8-elem frag
  const int b_lane = (tid >> 1) & 63;        // target fragment lane
  const int b_k32  = tid >> 7;               // target k32
  const int b_m    = b_lane & 15;
  const int b_quad = b_lane >> 4;
  const int b_jl   = b_k32 * 32 + b_quad * 8 + b_half * 4;  // j-local of elem 0
  const int b_slot = (b_jl >> 2) ^ b_m;      // sA slot holding group jl/4
  const float Eb  = Etab[(size_t)(rowbase + b_m) * 2];
  const float E2b = Etab[(size_t)(rowbase + b_m) * 2 + 1];

  const int t0 = wave * 2, t1 = wave * 2 + 1;
  f32x4 acc0 = z, acc1 = z, den = z;

  // ---- loop-carried per-lane DMA source pointers (R8 layout, 0 conflicts) ----
  const unsigned short* srcH[4];
  #pragma unroll
  for (int il = 0; il < 4; ++il) {
    const int i = wave * 4 + il;
    const int f = i * 8 + (lane >> 3);
    const int g = (lane & 7) ^ (lane >> 3);
    srcH[il] = ht + (size_t)f * NN + g * 8;
  }
  const int* srcA[2] = {nullptr, nullptr};
  int slotA[2] = {0, 0};
  if (wave >= 2) {
    #pragma unroll
    for (int q = 0; q < 2; ++q) {
      const int il = (wave - 2) * 2 + q;
      const int r = il * 4 + (lane >> 4);
      const int g = (lane & 15) ^ r;
      slotA[q] = il;
      srcA[q] = adj + (size_t)(rowbase + r) * NN + g * 4;
    }
  }
  const unsigned short* srcF = nullptr;
  if (wave == 1) {
    srcF = (lane < 8) ? (FbfF + lane * 8) : (FbfF2 + (lane - 8) * 8);
  }

  auto stage = [&](int b) {
    #pragma unroll
    for (int il = 0; il < 4; ++il) {
      async_cp16(&sH[b][(wave * 4 + il) * 512], srcH[il]);
      srcH[il] += 64;
    }
    if (wave >= 2) {
      #pragma unroll
      for (int q = 0; q < 2; ++q) {
        async_cp16(&sA[b][slotA[q] * 256], srcA[q]);
        srcA[q] += 64;
      }
    } else if (wave == 1 && lane < 16) {
      async_cp16(&sF[b][0], srcF);
      srcF += 64;
    }
  };

  stage(0);   // chunk 0 -> buffer 0

  for (int c = 0; c < 128; ++c) {
    const int cs = c & 1, ns = cs ^ 1;

    // Full barrier: drains DMA(c) (issued a whole chunk ago -> landed) and
    // fences last chunk's reads of buffer ns before its overwrite.
    __syncthreads();
    if (c + 1 < 128) stage(ns);   // DMA(c+1): flies across the lgkm-barrier below

    // ---- build phase: 4 weight elements per thread -> sAF[cs] ----
    {
      i32x4 av = *(const i32x4*)&sA[cs][b_m * 64 + b_slot * 4];
      unsigned long long fq = *(const unsigned long long*)&sF[cs][b_jl];
      unsigned long long gq = *(const unsigned long long*)&sF[cs][64 + b_jl];
      unsigned afp0 = 0, afp1 = 0;
      #pragma unroll
      for (int e = 0; e < 4; ++e) {
        const float F = bf2f((unsigned short)(fq >> (16 * e)));
        const float G = bf2f((unsigned short)(gq >> (16 * e)));
        const float w = fmaxf(Eb * F, E2b * G);
        const unsigned wb = av[e] ? (unsigned)f2bf(w) : 0u;
        if (e < 2) afp0 |= wb << (16 * e);
        else       afp1 |= wb << (16 * (e - 2));
      }
      u32x2 pkt; pkt[0] = afp0; pkt[1] = afp1;
      *(u32x2*)&sAF[cs][tid * 4] = pkt;
    }

    // lgkm-only barrier: af writes visible to all waves; DMA(c+1) vmcnt
    // deliberately NOT drained (0xC07F = vmcnt 63, expcnt 7, lgkmcnt 0).
    __builtin_amdgcn_s_waitcnt(0xC07F);
    __builtin_amdgcn_s_barrier();

    // ---- MFMA phase: pure LDS reads + MFMA ----
    #pragma unroll
    for (int k32 = 0; k32 < 2; ++k32) {
      bf16x8 af = __builtin_bit_cast(bf16x8,
          *(const u32x4*)&sAF[cs][k32 * 512 + lane * 8]);
      const int s0 = (k32 * 4 + quad) ^ (m & 7);
      bf16x8 b0 = __builtin_bit_cast(bf16x8,
          *(const u32x4*)&sH[cs][(t0 * 16 + m) * 64 + s0 * 8]);
      bf16x8 b1 = __builtin_bit_cast(bf16x8,
          *(const u32x4*)&sH[cs][(t1 * 16 + m) * 64 + s0 * 8]);
      acc0 = __builtin_amdgcn_mfma_f32_16x16x32_bf16(af, b0, acc0, 0, 0, 0);
      acc1 = __builtin_amdgcn_mfma_f32_16x16x32_bf16(af, b1, acc1, 0, 0, 0);
      den  = __builtin_amdgcn_mfma_f32_16x16x32_bf16(af, pones, den, 0, 0, 0);
    }
  }

  // ---- epilogue: wave-private rows x cols, direct store ----
  #pragma unroll
  for (int r = 0; r < 4; ++r) {
    const float inv = 1.0f / den[r];
    const int orow = rowbase + rowmap[r];
    const int c0 = t0 * 16 + colmap[r];
    const int c1 = t1 * 16 + colmap[r];
    out[(size_t)orow * FOUT + c0] = acc0[r] * inv + bias[c0];
    out[(size_t)orow * FOUT + c1] = acc1[r] * inv + bias[c1];
  }
}

// ---------------------------------------------------------------------------
extern "C" void kernel_launch(void* const* d_in, const int* in_sizes, int n_in,
                              void* d_out, int out_size, void* d_ws, size_t ws_size,
                              hipStream_t stream) {
  const float* x    = (const float*)d_in[0];
  const int*   adj  = (const int*)d_in[1];
  const float* W    = (const float*)d_in[2];
  const float* a1   = (const float*)d_in[3];
  const float* a2   = (const float*)d_in[4];
  const float* bias = (const float*)d_in[5];
  float* out = (float*)d_out;

  char* ws = (char*)d_ws;
  unsigned short* ht = (unsigned short*)ws;                            // 2 MB
  float* Etab = (float*)(ws + (size_t)2 * 1024 * 1024);                // 64 KB
  unsigned short* FbfF =
      (unsigned short*)(ws + (size_t)2 * 1024 * 1024 + 64 * 1024);     // 16 KB
  unsigned short* FbfF2 = FbfF + NN;                                   // 16 KB

  k_hw<<<NN / 8, 256, 0, stream>>>(x, W, a1, a2, ht, Etab, FbfF, FbfF2);
  k_gat<<<NN / 16, 256, 0, stream>>>(adj, ht, Etab, FbfF, FbfF2, bias, out);
}